// Round 2
// baseline (329.867 us; speedup 1.0000x reference)
//
#include <hip/hip_runtime.h>
#include <hip/hip_bf16.h>

#define B_   64
#define L_   2048
#define D_   512
#define SEG_ 8          // segments over L for the two gather/reduce passes
#define RPS_ 256        // rows per segment (L_/SEG_)

// ---------- helpers ----------

__device__ __forceinline__ float wave_sum(float x) {
#pragma unroll
  for (int off = 32; off > 0; off >>= 1) x += __shfl_down(x, off, 64);
  return x;  // valid in lane 0
}

__device__ __forceinline__ float dot8(float4 e0, float4 e1, float4 a0, float4 a1) {
  return e0.x * a0.x + e0.y * a0.y + e0.z * a0.z + e0.w * a0.w +
         e1.x * a1.x + e1.y * a1.y + e1.z * a1.z + e1.w * a1.w;
}

// ---------- K1: partial sums of embedding rows (for h) ----------
// grid (SEG_, B_), block 256 (4 waves). Each wave covers a full 512-col fp32
// row: lane loads float4 at col lane*4 and col 256+lane*4.
__global__ __launch_bounds__(256) void k_hpart(const int* __restrict__ tok,
                                               const float* __restrict__ emb,
                                               float* __restrict__ hpart) {
  const int seg = blockIdx.x, b = blockIdx.y;
  const int t = threadIdx.x, w = t >> 6, lane = t & 63;
  __shared__ int lt[RPS_];
  __shared__ float buf[4 * D_];
  lt[t] = tok[b * L_ + seg * RPS_ + t] + 1;
  __syncthreads();
  float acc[8];
#pragma unroll
  for (int j = 0; j < 8; ++j) acc[j] = 0.f;
#pragma unroll 8
  for (int it = 0; it < RPS_ / 4; ++it) {
    const int row = lt[it * 4 + w];
    const float4* rp = (const float4*)(emb + (size_t)row * D_);
    const float4 e0 = rp[lane];
    const float4 e1 = rp[lane + 64];
    acc[0] += e0.x; acc[1] += e0.y; acc[2] += e0.z; acc[3] += e0.w;
    acc[4] += e1.x; acc[5] += e1.y; acc[6] += e1.z; acc[7] += e1.w;
  }
  // cols: acc[0..3] -> lane*4+j ; acc[4..7] -> 256+lane*4+j
#pragma unroll
  for (int j = 0; j < 4; ++j) {
    buf[w * D_ + lane * 4 + j]       = acc[j];
    buf[w * D_ + 256 + lane * 4 + j] = acc[4 + j];
  }
  __syncthreads();
  const int c = 2 * t;
  float s0 = buf[c] + buf[D_ + c] + buf[2 * D_ + c] + buf[3 * D_ + c];
  float s1 = buf[c + 1] + buf[D_ + c + 1] + buf[2 * D_ + c + 1] + buf[3 * D_ + c + 1];
  float* o = hpart + ((size_t)seg * B_ + b) * D_;
  o[c] = s0; o[c + 1] = s1;
}

// ---------- K2: reduce h partials, v = W_b @ h / L ----------
// grid B_, block 256 (4 waves). Wave per output row d (strided by 4).
__global__ __launch_bounds__(256) void k_v(const float* __restrict__ hpart,
                                           const float* __restrict__ Wb,
                                           float* __restrict__ v) {
  const int b = blockIdx.x;
  const int t = threadIdx.x, w = t >> 6, lane = t & 63;
  __shared__ float sh[D_];
  float s0 = 0.f, s1 = 0.f;
  for (int s = 0; s < SEG_; ++s) {
    const float* hp = hpart + ((size_t)s * B_ + b) * D_;
    s0 += hp[2 * t]; s1 += hp[2 * t + 1];
  }
  sh[2 * t] = s0; sh[2 * t + 1] = s1;
  __syncthreads();
  const float4* shv = (const float4*)sh;
  const float4 a0 = shv[lane];        // cols lane*4 .. +3
  const float4 a1 = shv[lane + 64];   // cols 256+lane*4 .. +3
  for (int d = w; d < D_; d += 4) {
    const float4* rp = (const float4*)(Wb + (size_t)d * D_);
    float acc = dot8(rp[lane], rp[lane + 64], a0, a1);
    acc = wave_sum(acc);
    if (lane == 0) v[(size_t)b * D_ + d] = acc * (1.f / (float)L_);
  }
}

// ---------- K3: scores[b,l] = E[b,l,:] . v[b,:] ----------
// grid (L_/64, B_), block 256 (4 waves); wave per token row, 16 rows each.
__global__ __launch_bounds__(256) void k_scores(const int* __restrict__ tok,
                                                const float* __restrict__ emb,
                                                const float* __restrict__ v,
                                                float* __restrict__ scores) {
  const int chunk = blockIdx.x, b = blockIdx.y;
  const int t = threadIdx.x, w = t >> 6, lane = t & 63;
  __shared__ float sv[D_];
  sv[t] = v[(size_t)b * D_ + t];
  sv[t + 256] = v[(size_t)b * D_ + t + 256];
  __syncthreads();
  const float4* svv = (const float4*)sv;
  const float4 a0 = svv[lane], a1 = svv[lane + 64];
  const int l0 = chunk * 64 + w * 16;
#pragma unroll 4
  for (int i = 0; i < 16; ++i) {
    const int l = l0 + i;
    const int row = tok[b * L_ + l] + 1;
    const float4* rp = (const float4*)(emb + (size_t)row * D_);
    float acc = dot8(rp[lane], rp[lane + 64], a0, a1);
    acc = wave_sum(acc);
    if (lane == 0) scores[(size_t)b * L_ + l] = acc;
  }
}

// ---------- K4: softmax over L per doc, in place ----------
__global__ __launch_bounds__(256) void k_softmax(float* __restrict__ scores) {
  const int b = blockIdx.x;
  const int t = threadIdx.x, w = t >> 6, lane = t & 63;
  __shared__ float red[8];
  float s[8];
  float m = -1e30f;
#pragma unroll
  for (int k = 0; k < 8; ++k) {
    s[k] = scores[(size_t)b * L_ + t + 256 * k];
    m = fmaxf(m, s[k]);
  }
#pragma unroll
  for (int off = 32; off > 0; off >>= 1) m = fmaxf(m, __shfl_down(m, off, 64));
  if (lane == 0) red[w] = m;
  __syncthreads();
  m = fmaxf(fmaxf(red[0], red[1]), fmaxf(red[2], red[3]));
  float sum = 0.f;
#pragma unroll
  for (int k = 0; k < 8; ++k) { s[k] = __expf(s[k] - m); sum += s[k]; }
  sum = wave_sum(sum);
  if (lane == 0) red[4 + w] = sum;
  __syncthreads();
  const float inv = 1.f / (red[4] + red[5] + red[6] + red[7]);
#pragma unroll
  for (int k = 0; k < 8; ++k) scores[(size_t)b * L_ + t + 256 * k] = s[k] * inv;
}

// ---------- K5: weighted-sum partials ct = sum_l p[l]*E[l] ----------
__global__ __launch_bounds__(256) void k_ctpart(const int* __restrict__ tok,
                                                const float* __restrict__ emb,
                                                const float* __restrict__ p,
                                                float* __restrict__ ctpart) {
  const int seg = blockIdx.x, b = blockIdx.y;
  const int t = threadIdx.x, w = t >> 6, lane = t & 63;
  __shared__ int lt[RPS_];
  __shared__ float lw[RPS_];
  __shared__ float buf[4 * D_];
  lt[t] = tok[b * L_ + seg * RPS_ + t] + 1;
  lw[t] = p[(size_t)b * L_ + seg * RPS_ + t];
  __syncthreads();
  float acc[8];
#pragma unroll
  for (int j = 0; j < 8; ++j) acc[j] = 0.f;
#pragma unroll 8
  for (int it = 0; it < RPS_ / 4; ++it) {
    const int r = it * 4 + w;
    const int row = lt[r];
    const float wt = lw[r];
    const float4* rp = (const float4*)(emb + (size_t)row * D_);
    const float4 e0 = rp[lane];
    const float4 e1 = rp[lane + 64];
    acc[0] += wt * e0.x; acc[1] += wt * e0.y; acc[2] += wt * e0.z; acc[3] += wt * e0.w;
    acc[4] += wt * e1.x; acc[5] += wt * e1.y; acc[6] += wt * e1.z; acc[7] += wt * e1.w;
  }
#pragma unroll
  for (int j = 0; j < 4; ++j) {
    buf[w * D_ + lane * 4 + j]       = acc[j];
    buf[w * D_ + 256 + lane * 4 + j] = acc[4 + j];
  }
  __syncthreads();
  const int c = 2 * t;
  float s0 = buf[c] + buf[D_ + c] + buf[2 * D_ + c] + buf[3 * D_ + c];
  float s1 = buf[c + 1] + buf[D_ + c + 1] + buf[2 * D_ + c + 1] + buf[3 * D_ + c + 1];
  float* o = ctpart + ((size_t)seg * B_ + b) * D_;
  o[c] = s0; o[c + 1] = s1;
}

// ---------- K6: reduce ct partials, fp32 out ----------
__global__ __launch_bounds__(256) void k_out(const float* __restrict__ ctpart,
                                             float* __restrict__ out) {
  const int idx = blockIdx.x * 256 + threadIdx.x;  // 0 .. B_*D_-1
  float s = 0.f;
#pragma unroll
  for (int sg = 0; sg < SEG_; ++sg) s += ctpart[(size_t)sg * B_ * D_ + idx];
  out[idx] = s;
}

// ---------- launch ----------
extern "C" void kernel_launch(void* const* d_in, const int* in_sizes, int n_in,
                              void* d_out, int out_size, void* d_ws, size_t ws_size,
                              hipStream_t stream) {
  const int* tok = (const int*)d_in[0];
  const float* emb = (const float*)d_in[1];
  const float* Wb  = (const float*)d_in[2];
  float* out = (float*)d_out;
  float* ws = (float*)d_ws;

  float* hpart  = ws;                       // SEG_*B_*D_ = 262144 floats
  float* ctpart = ws + 262144;              // 262144 floats
  float* v      = ws + 524288;              // 32768 floats
  float* scores = ws + 557056;              // 131072 floats  (total ~2.75 MB)

  k_hpart  <<<dim3(SEG_, B_), 256, 0, stream>>>(tok, emb, hpart);
  k_v      <<<B_,             256, 0, stream>>>(hpart, Wb, v);
  k_scores <<<dim3(L_/64, B_),256, 0, stream>>>(tok, emb, v, scores);
  k_softmax<<<B_,             256, 0, stream>>>(scores);
  k_ctpart <<<dim3(SEG_, B_), 256, 0, stream>>>(tok, emb, scores, ctpart);
  k_out    <<<(B_*D_)/256,    256, 0, stream>>>(ctpart, out);
}

// Round 3
// 223.713 us; speedup vs baseline: 1.4745x; 1.4745x over previous
//
#include <hip/hip_runtime.h>
#include <hip/hip_bf16.h>

#define B_   64
#define L_   2048
#define D_   512
#define SEG_ 16         // segments over L for the two gather passes
#define RPS_ 128        // rows per segment (L_/SEG_)

// ---------- helpers ----------

// lane0-valid sum
__device__ __forceinline__ float wave_sum(float x) {
#pragma unroll
  for (int off = 32; off > 0; off >>= 1) x += __shfl_down(x, off, 64);
  return x;
}

// butterfly: all lanes get the sum
__device__ __forceinline__ float wave_sum_all(float x) {
#pragma unroll
  for (int m = 1; m < 64; m <<= 1) x += __shfl_xor(x, m, 64);
  return x;
}

__device__ __forceinline__ float dot8(float4 e0, float4 e1, float4 a0, float4 a1) {
  return e0.x * a0.x + e0.y * a0.y + e0.z * a0.z + e0.w * a0.w +
         e1.x * a1.x + e1.y * a1.y + e1.z * a1.z + e1.w * a1.w;
}

// ---------- K1: partial sums of embedding rows (for h) ----------
// grid (SEG_, B_) = 1024 blocks, block 256 (4 waves). Wave covers a full
// 512-col fp32 row: lane loads float4 at col lane*4 and col 256+lane*4.
__global__ __launch_bounds__(256) void k_hpart(const int* __restrict__ tok,
                                               const float* __restrict__ emb,
                                               float* __restrict__ A) {
  const int seg = blockIdx.x, b = blockIdx.y;
  const int t = threadIdx.x, w = t >> 6, lane = t & 63;
  __shared__ int lt[RPS_];
  __shared__ float buf[4 * D_];
  if (t < RPS_) lt[t] = tok[b * L_ + seg * RPS_ + t] + 1;
  __syncthreads();
  float acc[8];
#pragma unroll
  for (int j = 0; j < 8; ++j) acc[j] = 0.f;
#pragma unroll 8
  for (int it = 0; it < RPS_ / 4; ++it) {   // 32 rows per wave
    const int row = lt[it * 4 + w];
    const float4* rp = (const float4*)(emb + (size_t)row * D_);
    const float4 e0 = rp[lane];
    const float4 e1 = rp[lane + 64];
    acc[0] += e0.x; acc[1] += e0.y; acc[2] += e0.z; acc[3] += e0.w;
    acc[4] += e1.x; acc[5] += e1.y; acc[6] += e1.z; acc[7] += e1.w;
  }
#pragma unroll
  for (int j = 0; j < 4; ++j) {
    buf[w * D_ + lane * 4 + j]       = acc[j];
    buf[w * D_ + 256 + lane * 4 + j] = acc[4 + j];
  }
  __syncthreads();
  const int c = 2 * t;
  float s0 = buf[c] + buf[D_ + c] + buf[2 * D_ + c] + buf[3 * D_ + c];
  float s1 = buf[c + 1] + buf[D_ + c + 1] + buf[2 * D_ + c + 1] + buf[3 * D_ + c + 1];
  float* o = A + ((size_t)seg * B_ + b) * D_;
  o[c] = s0; o[c + 1] = s1;
}

// ---------- K2: v[b] = W_b @ h[b] / L ----------
// grid (8, B_) = 512 blocks. Block (g,b): reduce h[b] from A into LDS, then
// each wave computes 16 output rows d in [g*64 + w*16, +16).
__global__ __launch_bounds__(256) void k_v(const float* __restrict__ A,
                                           const float* __restrict__ Wb,
                                           float* __restrict__ v) {
  const int g = blockIdx.x, b = blockIdx.y;
  const int t = threadIdx.x, w = t >> 6, lane = t & 63;
  __shared__ float sh[D_];
  float s0 = 0.f, s1 = 0.f;
#pragma unroll
  for (int s = 0; s < SEG_; ++s) {
    const float* hp = A + ((size_t)s * B_ + b) * D_;
    s0 += hp[2 * t]; s1 += hp[2 * t + 1];
  }
  sh[2 * t] = s0; sh[2 * t + 1] = s1;
  __syncthreads();
  const float4* shv = (const float4*)sh;
  const float4 a0 = shv[lane];        // cols lane*4 .. +3
  const float4 a1 = shv[lane + 64];   // cols 256+lane*4 .. +3
  const int d0 = g * 64 + w * 16;
#pragma unroll 4
  for (int i = 0; i < 16; ++i) {
    const int d = d0 + i;
    const float4* rp = (const float4*)(Wb + (size_t)d * D_);
    float acc = dot8(rp[lane], rp[lane + 64], a0, a1);
    acc = wave_sum(acc);
    if (lane == 0) v[(size_t)b * D_ + d] = acc * (1.f / (float)L_);
  }
}

// ---------- K3: fused scores+softmax+weighted-sum (flash-style) ----------
// grid (SEG_, B_) = 1024 blocks. Per wave: online softmax over its 32 rows
// with register-resident acc[8]; block-combine across 4 waves; write
// per-segment unnormalized acc (at block max M) + (M, s_tot) to ws.
__global__ __launch_bounds__(256) void k_flash(const int* __restrict__ tok,
                                               const float* __restrict__ emb,
                                               const float* __restrict__ v,
                                               float* __restrict__ A,
                                               float* __restrict__ ms) {
  const int seg = blockIdx.x, b = blockIdx.y;
  const int t = threadIdx.x, w = t >> 6, lane = t & 63;
  __shared__ int lt[RPS_];
  __shared__ float sv[D_];
  __shared__ float red[4][2];
  __shared__ float buf[4 * D_];
  if (t < RPS_) lt[t] = tok[b * L_ + seg * RPS_ + t] + 1;
  sv[t] = v[(size_t)b * D_ + t];
  sv[t + 256] = v[(size_t)b * D_ + t + 256];
  __syncthreads();
  const float4* svv = (const float4*)sv;
  const float4 a0 = svv[lane], a1 = svv[lane + 64];
  float m = -1e30f, s = 0.f;
  float acc[8];
#pragma unroll
  for (int j = 0; j < 8; ++j) acc[j] = 0.f;
#pragma unroll 4
  for (int it = 0; it < RPS_ / 4; ++it) {   // 32 rows per wave
    const int row = lt[it * 4 + w];
    const float4* rp = (const float4*)(emb + (size_t)row * D_);
    const float4 e0 = rp[lane];
    const float4 e1 = rp[lane + 64];
    const float sc = wave_sum_all(dot8(e0, e1, a0, a1));
    const float mn = fmaxf(m, sc);
    const float al = __expf(m - mn);
    const float p  = __expf(sc - mn);
    s = s * al + p;
    acc[0] = acc[0] * al + p * e0.x; acc[1] = acc[1] * al + p * e0.y;
    acc[2] = acc[2] * al + p * e0.z; acc[3] = acc[3] * al + p * e0.w;
    acc[4] = acc[4] * al + p * e1.x; acc[5] = acc[5] * al + p * e1.y;
    acc[6] = acc[6] * al + p * e1.z; acc[7] = acc[7] * al + p * e1.w;
    m = mn;
  }
  if (lane == 0) { red[w][0] = m; red[w][1] = s; }
  __syncthreads();
  const float M = fmaxf(fmaxf(red[0][0], red[1][0]), fmaxf(red[2][0], red[3][0]));
  const float scw = __expf(m - M);     // m is wave-uniform
#pragma unroll
  for (int j = 0; j < 4; ++j) {
    buf[w * D_ + lane * 4 + j]       = acc[j] * scw;
    buf[w * D_ + 256 + lane * 4 + j] = acc[4 + j] * scw;
  }
  __syncthreads();
  const int c = 2 * t;
  float o0 = buf[c] + buf[D_ + c] + buf[2 * D_ + c] + buf[3 * D_ + c];
  float o1 = buf[c + 1] + buf[D_ + c + 1] + buf[2 * D_ + c + 1] + buf[3 * D_ + c + 1];
  float* oa = A + ((size_t)seg * B_ + b) * D_;   // A reuse: k_v already consumed it
  oa[c] = o0; oa[c + 1] = o1;
  if (t == 0) {
    float st = red[0][1] * __expf(red[0][0] - M) + red[1][1] * __expf(red[1][0] - M)
             + red[2][1] * __expf(red[2][0] - M) + red[3][1] * __expf(red[3][0] - M);
    ms[((size_t)seg * B_ + b) * 2]     = M;
    ms[((size_t)seg * B_ + b) * 2 + 1] = st;
  }
}

// ---------- K4: merge segment partials -> out ----------
__global__ __launch_bounds__(256) void k_merge(const float* __restrict__ A,
                                               const float* __restrict__ ms,
                                               float* __restrict__ out) {
  const int b = blockIdx.x;
  const int t = threadIdx.x;
  __shared__ float wseg[SEG_];
  if (t == 0) {
    float M = -1e30f;
#pragma unroll
    for (int s = 0; s < SEG_; ++s) M = fmaxf(M, ms[((size_t)s * B_ + b) * 2]);
    float den = 0.f;
#pragma unroll
    for (int s = 0; s < SEG_; ++s)
      den += ms[((size_t)s * B_ + b) * 2 + 1] * __expf(ms[((size_t)s * B_ + b) * 2] - M);
    const float inv = 1.f / den;
#pragma unroll
    for (int s = 0; s < SEG_; ++s)
      wseg[s] = __expf(ms[((size_t)s * B_ + b) * 2] - M) * inv;
  }
  __syncthreads();
  const int c = 2 * t;
  float o0 = 0.f, o1 = 0.f;
#pragma unroll
  for (int s = 0; s < SEG_; ++s) {
    const float* oa = A + ((size_t)s * B_ + b) * D_;
    const float ww = wseg[s];
    o0 += ww * oa[c]; o1 += ww * oa[c + 1];
  }
  out[(size_t)b * D_ + c] = o0;
  out[(size_t)b * D_ + c + 1] = o1;
}

// ---------- launch ----------
extern "C" void kernel_launch(void* const* d_in, const int* in_sizes, int n_in,
                              void* d_out, int out_size, void* d_ws, size_t ws_size,
                              hipStream_t stream) {
  const int* tok = (const int*)d_in[0];
  const float* emb = (const float*)d_in[1];
  const float* Wb  = (const float*)d_in[2];
  float* out = (float*)d_out;
  float* ws = (float*)d_ws;

  float* A  = ws;              // SEG_*B_*D_ = 524288 floats (h partials, then flash partials)
  float* v  = ws + 524288;     // B_*D_ = 32768 floats
  float* ms = ws + 557056;     // SEG_*B_*2 = 2048 floats   (total ~2.24 MB)

  k_hpart<<<dim3(SEG_, B_), 256, 0, stream>>>(tok, emb, A);
  k_v    <<<dim3(8, B_),    256, 0, stream>>>(A, Wb, v);
  k_flash<<<dim3(SEG_, B_), 256, 0, stream>>>(tok, emb, v, A, ms);
  k_merge<<<B_,             256, 0, stream>>>(A, ms, out);
}